// Round 18
// baseline (57.846 us; speedup 1.0000x reference)
//
#include <hip/hip_runtime.h>
#include <hip/hip_bf16.h>

// RisingTideAttentionV2: out[m,:] = norm( exp(-||x_m - p_n|| / efft_n) ) @ V
// M=16384, N=4096, D=128. d2 = x2[m] + p2[n] - 2*dot(x_m,p_n). NEURON_SCALE=0.05125
//
// r18 = r17 (best, 23.5us) + tide_norm folded into tide_main via a single
// global completion counter: the 2048th-arriving block normalizes (device-
// scope atomic loads; rows with rsum==0 -- all, on the common path -- need
// nothing since d_out is pre-zeroed). Common-path additions: one atomicAdd
// per block + one branch; the release fence runs ONLY if the cold path fired.
// 2 launches total.
//
// Screen: w = expf(-dist/efft) is EXACTLY 0.0f when dist >= 104*efft;
// thr = 106.7459*efft (154*ln2). Xb8 = fp8(-2x); mfma(A=-2x, B=p, C=x2+pc)
// emits e = x2+pc-2s directly. pc[n] = p2 - thr^2 - 40 (margin: false-
// negative needs d <= 104*efft <= 4.8 -> Sum|x.p| <= 147 -> fp8 err <= 38.4
// < 40, given guards ||x||^2<=400, ||p||^2<=100; NaN/Inf fail guards ->
// aflag). all e >= 0 (wave vote) ==> every weight exactly 0 ==> tile adds 0
// to numerator AND denominator ==> skip. Cold path: layout-free scalar f32
// from RAW inputs (exact; spurious triggers slow-but-correct).

typedef __attribute__((ext_vector_type(4))) float f32x4;
typedef __attribute__((ext_vector_type(4))) int   i32x4;
typedef __attribute__((ext_vector_type(8))) int   i32x8;

#define MTOT 16384
#define NTOT 4096
#define DD   128

__device__ __forceinline__ i32x4 pack16_fp8(f32x4 a0, f32x4 a1, f32x4 a2, f32x4 a3) {
    int w0 = __builtin_amdgcn_cvt_pk_fp8_f32(a0[0], a0[1], 0, false);
    w0     = __builtin_amdgcn_cvt_pk_fp8_f32(a0[2], a0[3], w0, true);
    int w1 = __builtin_amdgcn_cvt_pk_fp8_f32(a1[0], a1[1], 0, false);
    w1     = __builtin_amdgcn_cvt_pk_fp8_f32(a1[2], a1[3], w1, true);
    int w2 = __builtin_amdgcn_cvt_pk_fp8_f32(a2[0], a2[1], 0, false);
    w2     = __builtin_amdgcn_cvt_pk_fp8_f32(a2[2], a2[3], w2, true);
    int w3 = __builtin_amdgcn_cvt_pk_fp8_f32(a3[0], a3[1], 0, false);
    w3     = __builtin_amdgcn_cvt_pk_fp8_f32(a3[2], a3[3], w3, true);
    return (i32x4){w0, w1, w2, w3};
}

// ---------------- prep ----------------
// blocks 0..511:    X -> fp8(-2x) Xb8 + x2g (32 rows each; 8 thr/row)
// blocks 512..639:  pos/temp -> Pb8, pcg; val finite-scan (32 n each)
// blocks 640..1151: zero d_out (16 KB each)
// blocks 1152..1155: zero rsum_g; block 1152 zeroes aflag + mcnt
__global__ __launch_bounds__(256) void tide_prep(
    const float* __restrict__ x, const float* __restrict__ pos,
    const float* __restrict__ val, const float* __restrict__ temp,
    char* __restrict__ Xb8, float* __restrict__ x2g,
    char* __restrict__ Pb8, float* __restrict__ pcg,
    float* __restrict__ outz, float* __restrict__ rsz,
    int* __restrict__ aflag, int* __restrict__ mcnt)
{
    const int bid = blockIdx.x, tid = threadIdx.x;
    if (bid < 512) {
        const int row = bid * 32 + (tid >> 3), seg = tid & 7;
        const float* src = x + (size_t)row * DD + seg * 16;
        f32x4 a0 = ((const f32x4*)src)[0];
        f32x4 a1 = ((const f32x4*)src)[1];
        f32x4 a2 = ((const f32x4*)src)[2];
        f32x4 a3 = ((const f32x4*)src)[3];
        // store fp8(-2x): MFMA then computes -2*dot directly
        *(i32x4*)(Xb8 + (size_t)row * DD + seg * 16) =
            pack16_fp8(a0 * -2.f, a1 * -2.f, a2 * -2.f, a3 * -2.f);
        float s = a0[0]*a0[0]+a0[1]*a0[1]+a0[2]*a0[2]+a0[3]*a0[3]
                + a1[0]*a1[0]+a1[1]*a1[1]+a1[2]*a1[2]+a1[3]*a1[3]
                + a2[0]*a2[0]+a2[1]*a2[1]+a2[2]*a2[2]+a2[3]*a2[3]
                + a3[0]*a3[0]+a3[1]*a3[1]+a3[2]*a3[2]+a3[3]*a3[3];
        s += __shfl_xor(s, 1); s += __shfl_xor(s, 2); s += __shfl_xor(s, 4);
        if (seg == 0) {
            x2g[row] = s;
            if (!(s <= 400.f)) atomicOr(aflag, 1);   // NaN/Inf/out-of-model
        }
    } else if (bid < 640) {
        const int n = (bid - 512) * 32 + (tid >> 3), seg = tid & 7;
        const float* ps = pos + (size_t)n * DD + seg * 16;
        f32x4 a0 = ((const f32x4*)ps)[0];
        f32x4 a1 = ((const f32x4*)ps)[1];
        f32x4 a2 = ((const f32x4*)ps)[2];
        f32x4 a3 = ((const f32x4*)ps)[3];
        *(i32x4*)(Pb8 + (size_t)n * DD + seg * 16) = pack16_fp8(a0, a1, a2, a3);
        float s = a0[0]*a0[0]+a0[1]*a0[1]+a0[2]*a0[2]+a0[3]*a0[3]
                + a1[0]*a1[0]+a1[1]*a1[1]+a1[2]*a1[2]+a1[3]*a1[3]
                + a2[0]*a2[0]+a2[1]*a2[1]+a2[2]*a2[2]+a2[3]*a2[3]
                + a3[0]*a3[0]+a3[1]*a3[1]+a3[2]*a3[2]+a3[3]*a3[3];
        s += __shfl_xor(s, 1); s += __shfl_xor(s, 2); s += __shfl_xor(s, 4);
        if (seg == 0) {
            if (!(s <= 100.f)) atomicOr(aflag, 1);
            float efft = (fabsf(temp[n]) + 0.1f) * 0.05125f;
            float thr = 106.7459f * efft;           // 154*ln2
            float pcv = s - thr * thr - 40.0f;      // margin 40 covers fp8 err
            pcg[n] = pcv;
            if (!isfinite(pcv)) atomicOr(aflag, 1);
        }
        // V finite-scan (reference: 0-weight x NaN-V still taints output)
        const float* vs = val + (size_t)n * DD + seg * 16;
        f32x4 b0 = ((const f32x4*)vs)[0];
        f32x4 b1 = ((const f32x4*)vs)[1];
        f32x4 b2 = ((const f32x4*)vs)[2];
        f32x4 b3 = ((const f32x4*)vs)[3];
        float vchk = fabsf(b0[0])+fabsf(b0[1])+fabsf(b0[2])+fabsf(b0[3])
                   + fabsf(b1[0])+fabsf(b1[1])+fabsf(b1[2])+fabsf(b1[3])
                   + fabsf(b2[0])+fabsf(b2[1])+fabsf(b2[2])+fabsf(b2[3])
                   + fabsf(b3[0])+fabsf(b3[1])+fabsf(b3[2])+fabsf(b3[3]);
        if (!isfinite(vchk)) atomicOr(aflag, 1);
    } else if (bid < 1152) {
        f32x4 z = {0.f, 0.f, 0.f, 0.f};
        float* dst = outz + (size_t)(bid - 640) * 4096;
        #pragma unroll
        for (int j = 0; j < 4; ++j)
            *(f32x4*)(dst + (size_t)(tid + 256 * j) * 4) = z;
    } else {
        f32x4 z = {0.f, 0.f, 0.f, 0.f};
        float* dst = rsz + (size_t)(bid - 1152) * 4096;
        #pragma unroll
        for (int j = 0; j < 4; ++j)
            *(f32x4*)(dst + (size_t)(tid + 256 * j) * 4) = z;
        if (bid == 1152 && tid == 0) { aflag[0] = 0; mcnt[0] = 0; }
    }
}

// ---------------- main: fp8 K=128 screen + last-arrival normalize ----------
// grid = 2048: blockIdx = mc*16 + nb. Block: rows mc*128..+127, cols nb*256..+255.
// Wave w owns 64 cols; pf8 loop-invariant (32 VGPR). 16 KB fp8 X panel staged
// once via global_load_lds; 8 zero-sync subtiles of 2 ds_read + 4 MFMA(C=x2+pc)
// + min-tree. The 2048th-arriving block performs the (no-op on common path)
// normalization pass.
__global__ __launch_bounds__(256, 4) void tide_main(
    const char* __restrict__ Xb8, const float* __restrict__ x2g,
    const char* __restrict__ Pb8, const float* __restrict__ pcg,
    const float* __restrict__ x, const float* __restrict__ pos,
    const float* __restrict__ val, const float* __restrict__ temp,
    float* __restrict__ rsum_g, float* __restrict__ oaccum,
    const int* __restrict__ aflagp, int* __restrict__ mcnt)
{
    __shared__ __attribute__((aligned(16))) char xpanel[128 * DD];  // 16 KB fp8
    __shared__ __attribute__((aligned(16))) float x2t[128];
    __shared__ int lastFlag;

    const int tid = threadIdx.x;
    const int wid = tid >> 6, lane = tid & 63;
    const int lo = lane & 15, hi = lane >> 4;
    const int nb = blockIdx.x & 15, mc = blockIdx.x >> 4;
    const int mb = mc * 128;
    const int c0 = nb * 256 + wid * 64;
    const int sc = 0x7F7F7F7F;   // e8m0 127 in every byte = scale 1.0

    // loop-invariant P fragments: lane holds P[n=c0+f*16+lo][k-bytes hi*32..+32]
    // (A and B share the (hi,byte)->k placement, so any HW k-permutation
    //  cancels; C layout is the m89-verified 16x16 map: col=lane&15,
    //  row=(lane>>4)*4+reg -- matches x2[row]+pc[col] exactly.)
    i32x8 pf8[4];
    float pc[4];
    #pragma unroll
    for (int f = 0; f < 4; ++f) {
        const char* pb = Pb8 + (size_t)(c0 + f * 16 + lo) * DD + hi * 32;
        i32x4 plo = *(const i32x4*)pb;
        i32x4 phi = *(const i32x4*)(pb + 16);
        pf8[f] = (i32x8){plo[0], plo[1], plo[2], plo[3],
                         phi[0], phi[1], phi[2], phi[3]};
        pc[f] = pcg[c0 + f * 16 + lo];
    }
    const int af = aflagp[0];

    // stage 128x128 fp8 panel once: thread t covers rows (t>>3)+32i, 16B chunk
    // t&7; source chunk pre-swizzled by row&7 ((t>>3)&7, i-invariant), linear dest.
    const int srow = tid >> 3, sch = tid & 7;
    const char* xs = Xb8 + (size_t)(mb + srow) * DD + ((sch ^ (srow & 7)) * 16);
    char* ld = xpanel + tid * 16;
    #pragma unroll
    for (int i = 0; i < 4; ++i)
        __builtin_amdgcn_global_load_lds(
            (const __attribute__((address_space(1))) void*)(xs + (size_t)i * 32 * DD),
            (__attribute__((address_space(3))) void*)(ld + i * 4096), 16, 0, 0);
    if (tid < 128) x2t[tid] = x2g[mb + tid];
    __syncthreads();   // panel + x2 ready

    float em[4] = {3.4e38f, 3.4e38f, 3.4e38f, 3.4e38f};

    #pragma unroll
    for (int t = 0; t < 8; ++t) {
        // A-frag: row lo of subtile, k-bytes hi*32..+32 (chunks hi*2, hi*2+1)
        const char* xb = xpanel + (t * 16 + lo) * DD;
        i32x4 xa = *(const i32x4*)(xb + (((hi * 2)     ^ (lo & 7)) * 16));
        i32x4 xc = *(const i32x4*)(xb + (((hi * 2 + 1) ^ (lo & 7)) * 16));
        i32x8 xf8 = (i32x8){xa[0], xa[1], xa[2], xa[3],
                            xc[0], xc[1], xc[2], xc[3]};
        f32x4 x2r = *(const f32x4*)(x2t + t * 16 + hi * 4);

        // C-in = x2[row] + pc[col]; MFMA adds -2*dot -> output IS e
        f32x4 cc0, cc1, cc2, cc3;
        #pragma unroll
        for (int r = 0; r < 4; ++r) {
            cc0[r] = x2r[r] + pc[0];
            cc1[r] = x2r[r] + pc[1];
            cc2[r] = x2r[r] + pc[2];
            cc3[r] = x2r[r] + pc[3];
        }
        f32x4 e0 = __builtin_amdgcn_mfma_scale_f32_16x16x128_f8f6f4(
            xf8, pf8[0], cc0, 0, 0, 0, sc, 0, sc);
        f32x4 e1 = __builtin_amdgcn_mfma_scale_f32_16x16x128_f8f6f4(
            xf8, pf8[1], cc1, 0, 0, 0, sc, 0, sc);
        f32x4 e2 = __builtin_amdgcn_mfma_scale_f32_16x16x128_f8f6f4(
            xf8, pf8[2], cc2, 0, 0, 0, sc, 0, sc);
        f32x4 e3 = __builtin_amdgcn_mfma_scale_f32_16x16x128_f8f6f4(
            xf8, pf8[3], cc3, 0, 0, 0, sc, 0, sc);

        em[0] = fminf(em[0], fminf(fminf(e0[0], e0[1]), fminf(e0[2], e0[3])));
        em[1] = fminf(em[1], fminf(fminf(e1[0], e1[1]), fminf(e1[2], e1[3])));
        em[2] = fminf(em[2], fminf(fminf(e2[0], e2[1]), fminf(e2[2], e2[3])));
        em[3] = fminf(em[3], fminf(fminf(e3[0], e3[1]), fminf(e3[2], e3[3])));
    }

    const float emin = fminf(fminf(em[0], em[1]), fminf(em[2], em[3]));
    const int bad = (!(emin >= 0.f)) | af;
    int coldFired = 0;
    if (__builtin_expect(__any(bad), 0)) {
        coldFired = 1;
        // ---- cold exact path: scalar f32 from RAW inputs (layout-free) ----
        #pragma unroll 1
        for (int t = 0; t < 8; ++t) {
            #pragma unroll 1
            for (int f = 0; f < 4; ++f) {
                const int n = c0 + f * 16 + lo;
                float efft = (fabsf(temp[n]) + 0.1f) * 0.05125f;
                #pragma unroll 1
                for (int r = 0; r < 4; ++r) {
                    const int m = mb + t * 16 + hi * 4 + r;
                    float dot = 0.f, p2 = 0.f;
                    const float* xr = x + (size_t)m * DD;
                    const float* pr = pos + (size_t)n * DD;
                    #pragma unroll 4
                    for (int k = 0; k < DD; k += 4) {
                        f32x4 xv = *(const f32x4*)(xr + k);
                        f32x4 pv = *(const f32x4*)(pr + k);
                        dot = fmaf(xv[0], pv[0], dot); dot = fmaf(xv[1], pv[1], dot);
                        dot = fmaf(xv[2], pv[2], dot); dot = fmaf(xv[3], pv[3], dot);
                        p2  = fmaf(pv[0], pv[0], p2);  p2  = fmaf(pv[1], pv[1], p2);
                        p2  = fmaf(pv[2], pv[2], p2);  p2  = fmaf(pv[3], pv[3], p2);
                    }
                    float d2 = fmaxf(x2t[m - mb] + p2 - 2.f * dot, 0.f);
                    float wv = expf(-__builtin_amdgcn_sqrtf(d2) / efft);
                    if (wv != 0.f || af) {   // af: propagate 0*NaN-V like ref
                        atomicAdd(&rsum_g[m], wv);
                        const float* vr = val + (size_t)n * DD;
                        #pragma unroll 1
                        for (int dcol = 0; dcol < DD; ++dcol)
                            atomicAdd(&oaccum[(size_t)m * DD + dcol], wv * vr[dcol]);
                    }
                }
            }
        }
    }

    // ---- last-arrival normalize (no-op on common path) ----
    if (coldFired) __threadfence();      // release our atomics (cold only)
    if (tid == 0) {
        int old = atomicAdd(mcnt, 1);
        lastFlag = (old == 2047);
    }
    __syncthreads();
    if (lastFlag) {
        __threadfence();                 // acquire all blocks' writes
        #pragma unroll 1
        for (int j = 0; j < 64; ++j) {   // 256 threads x 64 rows = 16384
            const int row = j * 256 + tid;
            float s = __hip_atomic_load(&rsum_g[row], __ATOMIC_RELAXED,
                                        __HIP_MEMORY_SCOPE_AGENT);
            if (__builtin_expect(s != 0.f, 0)) {      // cold rows only
                float inv = 1.f / (s + 1e-8f);
                float* p = oaccum + (size_t)row * DD;
                #pragma unroll 1
                for (int dcol = 0; dcol < DD; ++dcol) {
                    float v = __hip_atomic_load(&p[dcol], __ATOMIC_RELAXED,
                                                __HIP_MEMORY_SCOPE_AGENT);
                    __hip_atomic_store(&p[dcol], v * inv, __ATOMIC_RELAXED,
                                       __HIP_MEMORY_SCOPE_AGENT);
                }
            }
            // s == 0: row already exact (0/(0+1e-8) = 0, pre-zeroed by prep)
        }
    }
}

extern "C" void kernel_launch(void* const* d_in, const int* in_sizes, int n_in,
                              void* d_out, int out_size, void* d_ws, size_t ws_size,
                              hipStream_t stream) {
    const float* x    = (const float*)d_in[0];  // [8,2048,128]
    const float* pos  = (const float*)d_in[1];  // [4096,128]
    const float* val  = (const float*)d_in[2];  // [4096,128]
    const float* temp = (const float*)d_in[3];  // [4096]
    float* out = (float*)d_out;

    char* ws = (char*)d_ws;
    char*  Xb8    = ws;                              // 2 MB
    char*  Pb8    = ws + 2097152;                    // 512 KB
    float* x2g    = (float*)(ws + 2621440);          // 64 KB
    float* pcg    = (float*)(ws + 2686976);          // 16 KB
    float* rsum_g = (float*)(ws + 2703360);          // 64 KB
    int*   aflag  = (int*)  (ws + 2768896);          // 4 B
    int*   mcnt   = (int*)  (ws + 2769152);          // 4 B

    hipLaunchKernelGGL(tide_prep, dim3(1156), dim3(256), 0, stream,
                       x, pos, val, temp, Xb8, x2g, Pb8, pcg, out, rsum_g,
                       aflag, mcnt);
    hipLaunchKernelGGL(tide_main, dim3(2048), dim3(256), 0, stream,
                       Xb8, x2g, Pb8, pcg, x, pos, val, temp, rsum_g, out,
                       aflag, mcnt);
}

// Round 19
// 23.778 us; speedup vs baseline: 2.4328x; 2.4328x over previous
//
#include <hip/hip_runtime.h>
#include <hip/hip_bf16.h>

// RisingTideAttentionV2: out[m,:] = norm( exp(-||x_m - p_n|| / efft_n) ) @ V
// M=16384, N=4096, D=128. d2 = x2[m] + p2[n] - 2*dot(x_m,p_n). NEURON_SCALE=0.05125
//
// FINAL (r19 = r17, best measured 23.5us; r18's fused-norm tail perturbed
// regalloc -- VGPR 64->40, pf8 demoted, main 12->48us -- reverted).
//
// Structure: 3 kernels. prep converts X -> fp8(-2x) + x2, P -> fp8 + pcg,
// zeroes d_out/rsum. main runs the screen: mfma_scale_f32_16x16x128_f8f6f4
// (A = fp8(-2x) panel from LDS, B = loop-invariant P fragments in registers,
// C = x2[row] + pc[col]) emits e = x2 + pc - 2s directly; all e >= 0 (one
// wave vote at the end) proves every weight in the 128x64 tile is EXACTLY
// 0.0f (w = expf(-d/efft) underflows for d >= 104*efft; thr = 106.7459*efft;
// pc = p2 - thr^2 - 40, margin 40 > worst-case fp8 dot error 38.4 given the
// prep-enforced guards ||x||^2<=400, ||p||^2<=100 -- NaN/Inf fail guards ->
// aflag -> cold). A skipped tile contributes exactly 0 to numerator AND
// denominator, so the common path does no PV/rsum work at all and d_out's
// pre-zeroed rows are bit-exact (0/(0+1e-8) = 0). Cold path (never taken for
// in-model data, exact for ANY input): layout-independent scalar f32 from the
// RAW inputs + atomics; spurious triggers are slow-but-correct. norm scales
// only rows with rsum != 0.

typedef __attribute__((ext_vector_type(4))) float f32x4;
typedef __attribute__((ext_vector_type(4))) int   i32x4;
typedef __attribute__((ext_vector_type(8))) int   i32x8;

#define MTOT 16384
#define NTOT 4096
#define DD   128

__device__ __forceinline__ i32x4 pack16_fp8(f32x4 a0, f32x4 a1, f32x4 a2, f32x4 a3) {
    int w0 = __builtin_amdgcn_cvt_pk_fp8_f32(a0[0], a0[1], 0, false);
    w0     = __builtin_amdgcn_cvt_pk_fp8_f32(a0[2], a0[3], w0, true);
    int w1 = __builtin_amdgcn_cvt_pk_fp8_f32(a1[0], a1[1], 0, false);
    w1     = __builtin_amdgcn_cvt_pk_fp8_f32(a1[2], a1[3], w1, true);
    int w2 = __builtin_amdgcn_cvt_pk_fp8_f32(a2[0], a2[1], 0, false);
    w2     = __builtin_amdgcn_cvt_pk_fp8_f32(a2[2], a2[3], w2, true);
    int w3 = __builtin_amdgcn_cvt_pk_fp8_f32(a3[0], a3[1], 0, false);
    w3     = __builtin_amdgcn_cvt_pk_fp8_f32(a3[2], a3[3], w3, true);
    return (i32x4){w0, w1, w2, w3};
}

// ---------------- prep ----------------
// blocks 0..511:    X -> fp8(-2x) Xb8 + x2g (32 rows each; 8 thr/row)
// blocks 512..639:  pos/temp -> Pb8, pcg; val finite-scan (32 n each)
// blocks 640..1151: zero d_out (16 KB each)
// blocks 1152..1155: zero rsum_g; block 1152 zeroes aflag
__global__ __launch_bounds__(256) void tide_prep(
    const float* __restrict__ x, const float* __restrict__ pos,
    const float* __restrict__ val, const float* __restrict__ temp,
    char* __restrict__ Xb8, float* __restrict__ x2g,
    char* __restrict__ Pb8, float* __restrict__ pcg,
    float* __restrict__ outz, float* __restrict__ rsz, int* __restrict__ aflag)
{
    const int bid = blockIdx.x, tid = threadIdx.x;
    if (bid < 512) {
        const int row = bid * 32 + (tid >> 3), seg = tid & 7;
        const float* src = x + (size_t)row * DD + seg * 16;
        f32x4 a0 = ((const f32x4*)src)[0];
        f32x4 a1 = ((const f32x4*)src)[1];
        f32x4 a2 = ((const f32x4*)src)[2];
        f32x4 a3 = ((const f32x4*)src)[3];
        // store fp8(-2x): MFMA then computes -2*dot directly
        *(i32x4*)(Xb8 + (size_t)row * DD + seg * 16) =
            pack16_fp8(a0 * -2.f, a1 * -2.f, a2 * -2.f, a3 * -2.f);
        float s = a0[0]*a0[0]+a0[1]*a0[1]+a0[2]*a0[2]+a0[3]*a0[3]
                + a1[0]*a1[0]+a1[1]*a1[1]+a1[2]*a1[2]+a1[3]*a1[3]
                + a2[0]*a2[0]+a2[1]*a2[1]+a2[2]*a2[2]+a2[3]*a2[3]
                + a3[0]*a3[0]+a3[1]*a3[1]+a3[2]*a3[2]+a3[3]*a3[3];
        s += __shfl_xor(s, 1); s += __shfl_xor(s, 2); s += __shfl_xor(s, 4);
        if (seg == 0) {
            x2g[row] = s;
            if (!(s <= 400.f)) atomicOr(aflag, 1);   // NaN/Inf/out-of-model
        }
    } else if (bid < 640) {
        const int n = (bid - 512) * 32 + (tid >> 3), seg = tid & 7;
        const float* ps = pos + (size_t)n * DD + seg * 16;
        f32x4 a0 = ((const f32x4*)ps)[0];
        f32x4 a1 = ((const f32x4*)ps)[1];
        f32x4 a2 = ((const f32x4*)ps)[2];
        f32x4 a3 = ((const f32x4*)ps)[3];
        *(i32x4*)(Pb8 + (size_t)n * DD + seg * 16) = pack16_fp8(a0, a1, a2, a3);
        float s = a0[0]*a0[0]+a0[1]*a0[1]+a0[2]*a0[2]+a0[3]*a0[3]
                + a1[0]*a1[0]+a1[1]*a1[1]+a1[2]*a1[2]+a1[3]*a1[3]
                + a2[0]*a2[0]+a2[1]*a2[1]+a2[2]*a2[2]+a2[3]*a2[3]
                + a3[0]*a3[0]+a3[1]*a3[1]+a3[2]*a3[2]+a3[3]*a3[3];
        s += __shfl_xor(s, 1); s += __shfl_xor(s, 2); s += __shfl_xor(s, 4);
        if (seg == 0) {
            if (!(s <= 100.f)) atomicOr(aflag, 1);
            float efft = (fabsf(temp[n]) + 0.1f) * 0.05125f;
            float thr = 106.7459f * efft;           // 154*ln2
            float pcv = s - thr * thr - 40.0f;      // margin 40 covers fp8 err
            pcg[n] = pcv;
            if (!isfinite(pcv)) atomicOr(aflag, 1);
        }
        // V finite-scan (reference: 0-weight x NaN-V still taints output)
        const float* vs = val + (size_t)n * DD + seg * 16;
        f32x4 b0 = ((const f32x4*)vs)[0];
        f32x4 b1 = ((const f32x4*)vs)[1];
        f32x4 b2 = ((const f32x4*)vs)[2];
        f32x4 b3 = ((const f32x4*)vs)[3];
        float vchk = fabsf(b0[0])+fabsf(b0[1])+fabsf(b0[2])+fabsf(b0[3])
                   + fabsf(b1[0])+fabsf(b1[1])+fabsf(b1[2])+fabsf(b1[3])
                   + fabsf(b2[0])+fabsf(b2[1])+fabsf(b2[2])+fabsf(b2[3])
                   + fabsf(b3[0])+fabsf(b3[1])+fabsf(b3[2])+fabsf(b3[3]);
        if (!isfinite(vchk)) atomicOr(aflag, 1);
    } else if (bid < 1152) {
        f32x4 z = {0.f, 0.f, 0.f, 0.f};
        float* dst = outz + (size_t)(bid - 640) * 4096;
        #pragma unroll
        for (int j = 0; j < 4; ++j)
            *(f32x4*)(dst + (size_t)(tid + 256 * j) * 4) = z;
    } else {
        f32x4 z = {0.f, 0.f, 0.f, 0.f};
        float* dst = rsz + (size_t)(bid - 1152) * 4096;
        #pragma unroll
        for (int j = 0; j < 4; ++j)
            *(f32x4*)(dst + (size_t)(tid + 256 * j) * 4) = z;
        if (bid == 1152 && tid == 0) aflag[0] = 0;
    }
}

// ---------------- main: fp8 K=128 screen with C-folded e ----------------
// grid = 2048: blockIdx = mc*16 + nb. Block: rows mc*128..+127, cols nb*256..+255.
// Wave w owns 64 cols; pf8 loop-invariant (32 VGPR). 16 KB fp8 X panel staged
// once via global_load_lds; 8 zero-sync subtiles of 2 ds_read + 4 MFMA(C=x2+pc)
// + min-tree. MFMA output IS the screen value e.
__global__ __launch_bounds__(256, 4) void tide_main(
    const char* __restrict__ Xb8, const float* __restrict__ x2g,
    const char* __restrict__ Pb8, const float* __restrict__ pcg,
    const float* __restrict__ x, const float* __restrict__ pos,
    const float* __restrict__ val, const float* __restrict__ temp,
    float* __restrict__ rsum_g, float* __restrict__ oaccum,
    const int* __restrict__ aflagp)
{
    __shared__ __attribute__((aligned(16))) char xpanel[128 * DD];  // 16 KB fp8
    __shared__ __attribute__((aligned(16))) float x2t[128];

    const int tid = threadIdx.x;
    const int wid = tid >> 6, lane = tid & 63;
    const int lo = lane & 15, hi = lane >> 4;
    const int nb = blockIdx.x & 15, mc = blockIdx.x >> 4;
    const int mb = mc * 128;
    const int c0 = nb * 256 + wid * 64;
    const int sc = 0x7F7F7F7F;   // e8m0 127 in every byte = scale 1.0

    // loop-invariant P fragments: lane holds P[n=c0+f*16+lo][k-bytes hi*32..+32]
    // (A and B use the same (hi,byte)->k placement, so any HW k-permutation
    //  cancels in the dot product; C layout is the m89-verified 16x16 map:
    //  col=lane&15, row=(lane>>4)*4+reg -- matches x2[row]+pc[col] exactly.)
    i32x8 pf8[4];
    float pc[4];
    #pragma unroll
    for (int f = 0; f < 4; ++f) {
        const char* pb = Pb8 + (size_t)(c0 + f * 16 + lo) * DD + hi * 32;
        i32x4 plo = *(const i32x4*)pb;
        i32x4 phi = *(const i32x4*)(pb + 16);
        pf8[f] = (i32x8){plo[0], plo[1], plo[2], plo[3],
                         phi[0], phi[1], phi[2], phi[3]};
        pc[f] = pcg[c0 + f * 16 + lo];
    }
    const int af = aflagp[0];

    // stage 128x128 fp8 panel once: thread t covers rows (t>>3)+32i, 16B chunk
    // t&7; source chunk pre-swizzled by row&7 ((t>>3)&7, i-invariant), linear dest.
    const int srow = tid >> 3, sch = tid & 7;
    const char* xs = Xb8 + (size_t)(mb + srow) * DD + ((sch ^ (srow & 7)) * 16);
    char* ld = xpanel + tid * 16;
    #pragma unroll
    for (int i = 0; i < 4; ++i)
        __builtin_amdgcn_global_load_lds(
            (const __attribute__((address_space(1))) void*)(xs + (size_t)i * 32 * DD),
            (__attribute__((address_space(3))) void*)(ld + i * 4096), 16, 0, 0);
    if (tid < 128) x2t[tid] = x2g[mb + tid];
    __syncthreads();   // the ONLY sync: panel + x2 ready

    float em[4] = {3.4e38f, 3.4e38f, 3.4e38f, 3.4e38f};

    #pragma unroll
    for (int t = 0; t < 8; ++t) {
        // A-frag: row lo of subtile, k-bytes hi*32..+32 (chunks hi*2, hi*2+1)
        const char* xb = xpanel + (t * 16 + lo) * DD;
        i32x4 xa = *(const i32x4*)(xb + (((hi * 2)     ^ (lo & 7)) * 16));
        i32x4 xc = *(const i32x4*)(xb + (((hi * 2 + 1) ^ (lo & 7)) * 16));
        i32x8 xf8 = (i32x8){xa[0], xa[1], xa[2], xa[3],
                            xc[0], xc[1], xc[2], xc[3]};
        f32x4 x2r = *(const f32x4*)(x2t + t * 16 + hi * 4);

        // C-in = x2[row] + pc[col]; MFMA adds -2*dot -> output IS e
        f32x4 cc0, cc1, cc2, cc3;
        #pragma unroll
        for (int r = 0; r < 4; ++r) {
            cc0[r] = x2r[r] + pc[0];
            cc1[r] = x2r[r] + pc[1];
            cc2[r] = x2r[r] + pc[2];
            cc3[r] = x2r[r] + pc[3];
        }
        f32x4 e0 = __builtin_amdgcn_mfma_scale_f32_16x16x128_f8f6f4(
            xf8, pf8[0], cc0, 0, 0, 0, sc, 0, sc);
        f32x4 e1 = __builtin_amdgcn_mfma_scale_f32_16x16x128_f8f6f4(
            xf8, pf8[1], cc1, 0, 0, 0, sc, 0, sc);
        f32x4 e2 = __builtin_amdgcn_mfma_scale_f32_16x16x128_f8f6f4(
            xf8, pf8[2], cc2, 0, 0, 0, sc, 0, sc);
        f32x4 e3 = __builtin_amdgcn_mfma_scale_f32_16x16x128_f8f6f4(
            xf8, pf8[3], cc3, 0, 0, 0, sc, 0, sc);

        // min-tree (min3-fusible nests)
        em[0] = fminf(em[0], fminf(fminf(e0[0], e0[1]), fminf(e0[2], e0[3])));
        em[1] = fminf(em[1], fminf(fminf(e1[0], e1[1]), fminf(e1[2], e1[3])));
        em[2] = fminf(em[2], fminf(fminf(e2[0], e2[1]), fminf(e2[2], e2[3])));
        em[3] = fminf(em[3], fminf(fminf(e3[0], e3[1]), fminf(e3[2], e3[3])));
    }

    const float emin = fminf(fminf(em[0], em[1]), fminf(em[2], em[3]));
    const int bad = (!(emin >= 0.f)) | af;
    if (__builtin_expect(__any(bad), 0)) {
        // ---- cold exact path: scalar f32 from RAW inputs (layout-free) ----
        #pragma unroll 1
        for (int t = 0; t < 8; ++t) {
            #pragma unroll 1
            for (int f = 0; f < 4; ++f) {
                const int n = c0 + f * 16 + lo;
                float efft = (fabsf(temp[n]) + 0.1f) * 0.05125f;
                #pragma unroll 1
                for (int r = 0; r < 4; ++r) {
                    const int m = mb + t * 16 + hi * 4 + r;
                    float dot = 0.f, p2 = 0.f;
                    const float* xr = x + (size_t)m * DD;
                    const float* pr = pos + (size_t)n * DD;
                    #pragma unroll 4
                    for (int k = 0; k < DD; k += 4) {
                        f32x4 xv = *(const f32x4*)(xr + k);
                        f32x4 pv = *(const f32x4*)(pr + k);
                        dot = fmaf(xv[0], pv[0], dot); dot = fmaf(xv[1], pv[1], dot);
                        dot = fmaf(xv[2], pv[2], dot); dot = fmaf(xv[3], pv[3], dot);
                        p2  = fmaf(pv[0], pv[0], p2);  p2  = fmaf(pv[1], pv[1], p2);
                        p2  = fmaf(pv[2], pv[2], p2);  p2  = fmaf(pv[3], pv[3], p2);
                    }
                    float d2 = fmaxf(x2t[m - mb] + p2 - 2.f * dot, 0.f);
                    float wv = expf(-__builtin_amdgcn_sqrtf(d2) / efft);
                    if (wv != 0.f || af) {   // af: propagate 0*NaN-V like ref
                        atomicAdd(&rsum_g[m], wv);
                        const float* vr = val + (size_t)n * DD;
                        #pragma unroll 1
                        for (int dcol = 0; dcol < DD; ++dcol)
                            atomicAdd(&oaccum[(size_t)m * DD + dcol], wv * vr[dcol]);
                    }
                }
            }
        }
    }
}

// ---------------- normalize: only rows with nonzero rsum need work ----------
__global__ __launch_bounds__(256) void tide_norm(
    const float* __restrict__ rsum_g, float* __restrict__ outp)
{
    const int row = blockIdx.x * 256 + threadIdx.x;
    float s = rsum_g[row];
    if (s != 0.f) {
        float inv = 1.f / (s + 1e-8f);
        float* p = outp + (size_t)row * DD;
        #pragma unroll 4
        for (int j = 0; j < DD / 4; ++j) {
            f32x4 v = *(f32x4*)(p + j * 4);
            v[0] *= inv; v[1] *= inv; v[2] *= inv; v[3] *= inv;
            *(f32x4*)(p + j * 4) = v;
        }
    }
    // s == 0: out row already exact (0 / (0 + 1e-8) = 0, pre-zeroed)
}

extern "C" void kernel_launch(void* const* d_in, const int* in_sizes, int n_in,
                              void* d_out, int out_size, void* d_ws, size_t ws_size,
                              hipStream_t stream) {
    const float* x    = (const float*)d_in[0];  // [8,2048,128]
    const float* pos  = (const float*)d_in[1];  // [4096,128]
    const float* val  = (const float*)d_in[2];  // [4096,128]
    const float* temp = (const float*)d_in[3];  // [4096]
    float* out = (float*)d_out;

    char* ws = (char*)d_ws;
    char*  Xb8    = ws;                              // 2 MB
    char*  Pb8    = ws + 2097152;                    // 512 KB
    float* x2g    = (float*)(ws + 2621440);          // 64 KB
    float* pcg    = (float*)(ws + 2686976);          // 16 KB
    float* rsum_g = (float*)(ws + 2703360);          // 64 KB
    int*   aflag  = (int*)  (ws + 2768896);          // 4 B

    hipLaunchKernelGGL(tide_prep, dim3(1156), dim3(256), 0, stream,
                       x, pos, val, temp, Xb8, x2g, Pb8, pcg, out, rsum_g, aflag);
    hipLaunchKernelGGL(tide_main, dim3(2048), dim3(256), 0, stream,
                       Xb8, x2g, Pb8, pcg, x, pos, val, temp, rsum_g, out, aflag);
    hipLaunchKernelGGL(tide_norm, dim3(64), dim3(256), 0, stream,
                       rsum_g, out);
}